// Round 1
// baseline (251.412 us; speedup 1.0000x reference)
//
#include <hip/hip_runtime.h>
#include <math.h>

// Problem: x[128, 1, 512, 512] fp32.
//   pred = softplus(x); m = max(pred) per sample; out = m > 1e-8 ? pred/m : pred
// softplus is strictly monotone -> per-sample max of pred == softplus(max of raw x).
// Pass A: raw-max reduce per sample (no transcendentals in the hot loop),
//         softplus applied once per block-max, atomicMax on positive-float bits.
// Pass B: recompute softplus per element, scale, write. Re-read of x likely hits
//         the 256 MiB Infinity Cache (input is 134 MB).

#define PER_SAMPLE (512 * 512)                       // 262144 floats / sample
#define F4_PER_SAMPLE (PER_SAMPLE / 4)               // 65536 float4
#define BLOCKS_PER_SAMPLE 16
#define THREADS 256
#define F4_PER_BLOCK (F4_PER_SAMPLE / BLOCKS_PER_SAMPLE) // 4096 float4
#define F4_PER_THREAD (F4_PER_BLOCK / THREADS)           // 16 float4 / thread

__device__ __forceinline__ float softplus_f(float x) {
    // max(x,0) + log1p(exp(-|x|)); fast-intrinsic variant.
    // arg of __expf is in (-inf, 0], result in (0,1]; 1+t rounding gives
    // absolute error <= ~6e-8 in the output — far below the 2e-2 threshold.
    return fmaxf(x, 0.0f) + __logf(1.0f + __expf(-fabsf(x)));
}

__global__ __launch_bounds__(THREADS) void rawmax_kernel(
        const float* __restrict__ x, float* __restrict__ smax) {
    const int sample = blockIdx.x / BLOCKS_PER_SAMPLE;
    const int part   = blockIdx.x % BLOCKS_PER_SAMPLE;
    const int t      = threadIdx.x;

    const float4* x4 = (const float4*)x +
        (size_t)sample * F4_PER_SAMPLE + (size_t)part * F4_PER_BLOCK;

    float m = -INFINITY;
#pragma unroll
    for (int i = 0; i < F4_PER_THREAD; ++i) {
        float4 v = x4[(size_t)i * THREADS + t];
        m = fmaxf(m, fmaxf(fmaxf(v.x, v.y), fmaxf(v.z, v.w)));
    }

    // wave64 shuffle reduction
#pragma unroll
    for (int off = 32; off > 0; off >>= 1)
        m = fmaxf(m, __shfl_down(m, off, 64));

    __shared__ float wmax[THREADS / 64];
    if ((t & 63) == 0) wmax[t >> 6] = m;
    __syncthreads();

    if (t == 0) {
        float bm = wmax[0];
#pragma unroll
        for (int w = 1; w < THREADS / 64; ++w) bm = fmaxf(bm, wmax[w]);
        // softplus(block raw max) > 0 always -> int-bits atomicMax is order-
        // preserving; workspace slot pre-zeroed (0.0f bits == 0).
        float sp = softplus_f(bm);
        atomicMax((int*)&smax[sample], __float_as_int(sp));
    }
}

__global__ __launch_bounds__(THREADS) void scale_kernel(
        const float* __restrict__ x, const float* __restrict__ smax,
        float* __restrict__ out) {
    const int sample = blockIdx.x / BLOCKS_PER_SAMPLE;
    const int part   = blockIdx.x % BLOCKS_PER_SAMPLE;
    const int t      = threadIdx.x;

    const size_t base =
        (size_t)sample * F4_PER_SAMPLE + (size_t)part * F4_PER_BLOCK;
    const float4* x4 = (const float4*)x + base;
    float4* o4       = (float4*)out + base;

    const float m     = smax[sample];           // uniform per block -> s_load
    const float scale = (m > 1e-8f) ? (1.0f / m) : 1.0f;

#pragma unroll
    for (int i = 0; i < F4_PER_THREAD; ++i) {
        float4 v = x4[(size_t)i * THREADS + t];
        float4 r;
        r.x = softplus_f(v.x) * scale;
        r.y = softplus_f(v.y) * scale;
        r.z = softplus_f(v.z) * scale;
        r.w = softplus_f(v.w) * scale;
        o4[(size_t)i * THREADS + t] = r;
    }
}

extern "C" void kernel_launch(void* const* d_in, const int* in_sizes, int n_in,
                              void* d_out, int out_size, void* d_ws, size_t ws_size,
                              hipStream_t stream) {
    const float* x = (const float*)d_in[0];
    float* out     = (float*)d_out;
    float* smax    = (float*)d_ws;

    const int n_total   = in_sizes[0];
    const int n_samples = n_total / PER_SAMPLE;     // 128
    const int grid      = n_samples * BLOCKS_PER_SAMPLE; // 2048 blocks

    // zero the per-sample max slots (ws is re-poisoned to 0xAA before every call)
    hipMemsetAsync(d_ws, 0, (size_t)n_samples * sizeof(float), stream);

    rawmax_kernel<<<grid, THREADS, 0, stream>>>(x, smax);
    scale_kernel<<<grid, THREADS, 0, stream>>>(x, smax, out);
}

// Round 3
// 248.678 us; speedup vs baseline: 1.0110x; 1.0110x over previous
//
#include <hip/hip_runtime.h>
#include <math.h>

// Problem: x[128, 1, 512, 512] fp32.
//   pred = softplus(x); m = max(pred) per sample; out = m > 1e-8 ? pred/m : pred
// softplus is strictly monotone -> per-sample max of pred == softplus(per-sample
// raw max of x).
//
// Pass A: per-block raw-max partials -> ws[2048] (no atomics, no ws init).
// Pass B: first wave reduces the sample's 16 partials, softplus once, broadcast
//         scale via LDS; then streaming softplus*scale with NONTEMPORAL stores
//         (native ext_vector_type float4 — HIP_vector_type is rejected by the
//         builtin) so the 134 MB `out` write stream doesn't evict x from the
//         256 MiB L3 (x re-read should be L3-resident: pass-B HBM FETCH ~ 0).

#define PER_SAMPLE (512 * 512)                       // 262144 floats / sample
#define F4_PER_SAMPLE (PER_SAMPLE / 4)               // 65536 float4
#define BLOCKS_PER_SAMPLE 16
#define THREADS 256
#define F4_PER_BLOCK (F4_PER_SAMPLE / BLOCKS_PER_SAMPLE) // 4096 float4
#define F4_PER_THREAD (F4_PER_BLOCK / THREADS)           // 16 float4 / thread

typedef float f32x4 __attribute__((ext_vector_type(4)));

__device__ __forceinline__ float softplus_f(float x) {
    // max(x,0) + log1p(exp(-|x|)); abs err ~6e-8 << 2e-2 threshold.
    return fmaxf(x, 0.0f) + __logf(1.0f + __expf(-fabsf(x)));
}

__global__ __launch_bounds__(THREADS) void rawmax_kernel(
        const float* __restrict__ x, float* __restrict__ partials) {
    const int sample = blockIdx.x / BLOCKS_PER_SAMPLE;
    const int part   = blockIdx.x % BLOCKS_PER_SAMPLE;
    const int t      = threadIdx.x;

    const f32x4* x4 = (const f32x4*)x +
        (size_t)sample * F4_PER_SAMPLE + (size_t)part * F4_PER_BLOCK;

    float m = -INFINITY;
#pragma unroll
    for (int i = 0; i < F4_PER_THREAD; ++i) {
        f32x4 v = x4[(size_t)i * THREADS + t];
        m = fmaxf(m, fmaxf(fmaxf(v.x, v.y), fmaxf(v.z, v.w)));
    }

    // wave64 shuffle reduction
#pragma unroll
    for (int off = 32; off > 0; off >>= 1)
        m = fmaxf(m, __shfl_down(m, off, 64));

    __shared__ float wmax[THREADS / 64];
    if ((t & 63) == 0) wmax[t >> 6] = m;
    __syncthreads();

    if (t == 0) {
        float bm = wmax[0];
#pragma unroll
        for (int w = 1; w < THREADS / 64; ++w) bm = fmaxf(bm, wmax[w]);
        partials[blockIdx.x] = bm;   // raw max, softplus deferred to pass B
    }
}

__global__ __launch_bounds__(THREADS) void scale_kernel(
        const float* __restrict__ x, const float* __restrict__ partials,
        float* __restrict__ out) {
    const int sample = blockIdx.x / BLOCKS_PER_SAMPLE;
    const int part   = blockIdx.x % BLOCKS_PER_SAMPLE;
    const int t      = threadIdx.x;

    // ---- prologue: reduce this sample's 16 partials, broadcast scale ----
    __shared__ float s_scale;
    if (t < 64) {
        float p = (t < BLOCKS_PER_SAMPLE)
                    ? partials[sample * BLOCKS_PER_SAMPLE + t] : -INFINITY;
#pragma unroll
        for (int off = 8; off > 0; off >>= 1)      // butterfly within 16 lanes
            p = fmaxf(p, __shfl_xor(p, off, 64));
        if (t == 0) {
            float m = softplus_f(p);               // m > 0 always
            s_scale = (m > 1e-8f) ? (1.0f / m) : 1.0f;
        }
    }
    __syncthreads();
    const float scale = s_scale;

    // ---- streaming softplus * scale, nontemporal stores ----
    const size_t base =
        (size_t)sample * F4_PER_SAMPLE + (size_t)part * F4_PER_BLOCK;
    const f32x4* x4 = (const f32x4*)x + base;
    f32x4* o4       = (f32x4*)out + base;

#pragma unroll
    for (int i = 0; i < F4_PER_THREAD; ++i) {
        f32x4 v = x4[(size_t)i * THREADS + t];
        f32x4 r;
        r.x = softplus_f(v.x) * scale;
        r.y = softplus_f(v.y) * scale;
        r.z = softplus_f(v.z) * scale;
        r.w = softplus_f(v.w) * scale;
        __builtin_nontemporal_store(r, &o4[(size_t)i * THREADS + t]);
    }
}

extern "C" void kernel_launch(void* const* d_in, const int* in_sizes, int n_in,
                              void* d_out, int out_size, void* d_ws, size_t ws_size,
                              hipStream_t stream) {
    const float* x  = (const float*)d_in[0];
    float* out      = (float*)d_out;
    float* partials = (float*)d_ws;                 // 2048 floats, fully written

    const int n_total   = in_sizes[0];
    const int n_samples = n_total / PER_SAMPLE;          // 128
    const int grid      = n_samples * BLOCKS_PER_SAMPLE; // 2048 blocks

    rawmax_kernel<<<grid, THREADS, 0, stream>>>(x, partials);
    scale_kernel<<<grid, THREADS, 0, stream>>>(x, partials, out);
}

// Round 5
// 248.260 us; speedup vs baseline: 1.0127x; 1.0017x over previous
//
#include <hip/hip_runtime.h>
#include <math.h>

// Problem: x[128, 1, 512, 512] fp32.
//   pred = softplus(x); m = max(pred) per sample; out = m > 1e-8 ? pred/m : pred
// softplus is strictly monotone -> per-sample max of pred == softplus(raw max).
//
// R5: two-kernel structure (cooperative launch fails on this harness — R4).
// Both hot loops restructured into explicit 4-load batches (all loads issued
// before any use) to guarantee >=4 outstanding global_load_dwordx4 per wave,
// mirroring the 6.29 TB/s float4-copy microbenchmark pattern.
// Pass A: per-block raw-max partials -> ws (no atomics, no ws init).
// Pass B: reduce 16 partials in-prologue, softplus once, broadcast scale;
//         stream softplus*scale with nontemporal stores (keep x L3-resident).

#define PER_SAMPLE (512 * 512)                       // 262144 floats / sample
#define F4_PER_SAMPLE (PER_SAMPLE / 4)               // 65536 float4
#define BLOCKS_PER_SAMPLE 16
#define THREADS 256
#define F4_PER_BLOCK (F4_PER_SAMPLE / BLOCKS_PER_SAMPLE) // 4096 float4
#define F4_PER_THREAD (F4_PER_BLOCK / THREADS)           // 16 float4 / thread
#define BATCH 4                                          // loads in flight

typedef float f32x4 __attribute__((ext_vector_type(4)));

__device__ __forceinline__ float softplus_f(float x) {
    // max(x,0) + log1p(exp(-|x|)); abs err ~6e-8 << 2e-2 threshold.
    return fmaxf(x, 0.0f) + __logf(1.0f + __expf(-fabsf(x)));
}

__global__ __launch_bounds__(THREADS) void rawmax_kernel(
        const float* __restrict__ x, float* __restrict__ partials) {
    const int sample = blockIdx.x / BLOCKS_PER_SAMPLE;
    const int part   = blockIdx.x % BLOCKS_PER_SAMPLE;
    const int t      = threadIdx.x;

    const f32x4* x4 = (const f32x4*)x +
        (size_t)sample * F4_PER_SAMPLE + (size_t)part * F4_PER_BLOCK;

    float m = -INFINITY;
#pragma unroll
    for (int b = 0; b < F4_PER_THREAD / BATCH; ++b) {
        f32x4 v[BATCH];
#pragma unroll
        for (int j = 0; j < BATCH; ++j)              // 4 loads back-to-back
            v[j] = x4[(size_t)(b * BATCH + j) * THREADS + t];
#pragma unroll
        for (int j = 0; j < BATCH; ++j)
            m = fmaxf(m, fmaxf(fmaxf(v[j].x, v[j].y), fmaxf(v[j].z, v[j].w)));
    }

    // wave64 shuffle reduction
#pragma unroll
    for (int off = 32; off > 0; off >>= 1)
        m = fmaxf(m, __shfl_down(m, off, 64));

    __shared__ float wmax[THREADS / 64];
    if ((t & 63) == 0) wmax[t >> 6] = m;
    __syncthreads();

    if (t == 0) {
        float bm = wmax[0];
#pragma unroll
        for (int w = 1; w < THREADS / 64; ++w) bm = fmaxf(bm, wmax[w]);
        partials[blockIdx.x] = bm;   // raw max, softplus deferred to pass B
    }
}

__global__ __launch_bounds__(THREADS) void scale_kernel(
        const float* __restrict__ x, const float* __restrict__ partials,
        float* __restrict__ out) {
    const int sample = blockIdx.x / BLOCKS_PER_SAMPLE;
    const int part   = blockIdx.x % BLOCKS_PER_SAMPLE;
    const int t      = threadIdx.x;

    // ---- prologue: reduce this sample's 16 partials, broadcast scale ----
    __shared__ float s_scale;
    if (t < 64) {
        float p = (t < BLOCKS_PER_SAMPLE)
                    ? partials[sample * BLOCKS_PER_SAMPLE + t] : -INFINITY;
#pragma unroll
        for (int off = 8; off > 0; off >>= 1)      // butterfly within 16 lanes
            p = fmaxf(p, __shfl_xor(p, off, 64));
        if (t == 0) {
            float m = softplus_f(p);               // m > 0 always
            s_scale = (m > 1e-8f) ? (1.0f / m) : 1.0f;
        }
    }
    __syncthreads();
    const float scale = s_scale;

    // ---- streaming softplus * scale, batched loads + nontemporal stores ----
    const size_t base =
        (size_t)sample * F4_PER_SAMPLE + (size_t)part * F4_PER_BLOCK;
    const f32x4* x4 = (const f32x4*)x + base;
    f32x4* o4       = (f32x4*)out + base;

#pragma unroll
    for (int b = 0; b < F4_PER_THREAD / BATCH; ++b) {
        f32x4 v[BATCH];
#pragma unroll
        for (int j = 0; j < BATCH; ++j)              // 4 loads back-to-back
            v[j] = x4[(size_t)(b * BATCH + j) * THREADS + t];
#pragma unroll
        for (int j = 0; j < BATCH; ++j) {
            f32x4 r;
            r.x = softplus_f(v[j].x) * scale;
            r.y = softplus_f(v[j].y) * scale;
            r.z = softplus_f(v[j].z) * scale;
            r.w = softplus_f(v[j].w) * scale;
            __builtin_nontemporal_store(
                r, &o4[(size_t)(b * BATCH + j) * THREADS + t]);
        }
    }
}

extern "C" void kernel_launch(void* const* d_in, const int* in_sizes, int n_in,
                              void* d_out, int out_size, void* d_ws, size_t ws_size,
                              hipStream_t stream) {
    const float* x  = (const float*)d_in[0];
    float* out      = (float*)d_out;
    float* partials = (float*)d_ws;                 // 2048 floats, fully written

    const int n_total   = in_sizes[0];
    const int n_samples = n_total / PER_SAMPLE;          // 128
    const int grid      = n_samples * BLOCKS_PER_SAMPLE; // 2048 blocks

    rawmax_kernel<<<grid, THREADS, 0, stream>>>(x, partials);
    scale_kernel<<<grid, THREADS, 0, stream>>>(x, partials, out);
}